// Round 7
// baseline (47.995 us; speedup 1.0000x reference)
//
#include <hip/hip_runtime.h>
#include <math.h>

#define TWO_PI_F 6.28318530717958647692f

typedef unsigned int u32;
typedef __attribute__((ext_vector_type(4))) u32      u32x4;
typedef __attribute__((ext_vector_type(4))) float    f4;
typedef __attribute__((ext_vector_type(2))) _Float16 h2;

union V8 { u32x4 v; h2 h[4]; };

// --- forced VOP3P packed f16 ops (compiler scalarizes vector _Float16) ---
__device__ __forceinline__ h2 pk_mul(h2 a, h2 b) {
    u32 d, ua = __builtin_bit_cast(u32, a), ub = __builtin_bit_cast(u32, b);
    asm("v_pk_mul_f16 %0, %1, %2" : "=v"(d) : "v"(ua), "v"(ub));
    return __builtin_bit_cast(h2, d);
}
__device__ __forceinline__ h2 pk_add(h2 a, h2 b) {
    u32 d, ua = __builtin_bit_cast(u32, a), ub = __builtin_bit_cast(u32, b);
    asm("v_pk_add_f16 %0, %1, %2" : "=v"(d) : "v"(ua), "v"(ub));
    return __builtin_bit_cast(h2, d);
}
__device__ __forceinline__ h2 pk_fma(h2 a, h2 b, h2 c) {
    u32 d, ua = __builtin_bit_cast(u32, a), ub = __builtin_bit_cast(u32, b),
        uc = __builtin_bit_cast(u32, c);
    asm("v_pk_fma_f16 %0, %1, %2, %3" : "=v"(d) : "v"(ua), "v"(ub), "v"(uc));
    return __builtin_bit_cast(h2, d);
}
__device__ __forceinline__ h2 habs2(h2 a) {   // packed abs = clear sign bits
    u32 x = __builtin_bit_cast(u32, a) & 0x7fff7fffu;
    return __builtin_bit_cast(h2, x);
}

// ---------------------------------------------------------------------------
// Fused kernel, relu split as relu(x) = 0.5(x + |x|):
//   out(i,j) = b2 + 0.25(P[i]+P[j]) + 0.5(ct*Lc + st*Ls)   [separable, f32]
//            + sum_h (0.25*w2[h]) * (|p1(h)| + |p2(h)|)     [elementwise, pk f16]
// where p1 = A[i,h]+B[j,h]+d2, p2 = A[j,h]+B[i,h]+d2, d2 = ct*wc[h]+st*ws[h],
//       P[r] = sum_h w2[h]*(A[r,h]+B[r,h]), Lc = sum w2*wc, Ls = sum w2*ws.
// One 64x64 tile per block, upper-triangular blocks; A/B generated in-LDS.
// ---------------------------------------------------------------------------
__global__ __launch_bounds__(512, 4) void gd_fused(
    const float* __restrict__ z,  const float* __restrict__ s,
    const float* __restrict__ W1, const float* __restrict__ b1,
    const float* __restrict__ W2, const float* __restrict__ b2v,
    float* __restrict__ out, int N, int NB)
{
    __shared__ __attribute__((aligned(16))) _Float16 sAB[4][64][64]; // Ai,Bi,Aj,Bj
    __shared__ __attribute__((aligned(16))) _Float16 sWc[64], sWs[64], sW2[64];
    __shared__ float strig[4][128];   // c1,s1,c2,s2 per local row (0:63=i, 64:127=j)
    __shared__ float zc[64];
    __shared__ float sPq[128];        // 0.25 * P[row]
    __shared__ float sLc, sLs;        // 0.5 * Lc, 0.5 * Ls

    // --- triangular block decode: u -> (bi, bj), bj >= bi ---
    int u = blockIdx.x;
    int M = 2 * NB + 1;
    float disc = (float)(M * M - 8 * u);
    int bi = (int)(((float)M - sqrtf(disc)) * 0.5f);
    if (bi < 0) bi = 0;
    if (bi > NB - 1) bi = NB - 1;
    while (bi > 0 && bi * (M - bi) / 2 > u) --bi;
    while ((bi + 1) * (M - (bi + 1)) / 2 <= u) ++bi;
    int bj = bi + (u - bi * (M - bi) / 2);

    int t = threadIdx.x;

    // --- setup phase: disjoint thread ranges, one barrier ---
    if (t < 64) {                       // zc = b1 + z @ W1[10:42] ; Lc/Ls reduce
        float acc = b1[t];
#pragma unroll
        for (int zz = 0; zz < 32; ++zz)
            acc = fmaf(z[zz], W1[(10 + zz) * 64 + t], acc);
        zc[t] = acc;
        float w2f = W2[t];
        float lc = w2f * W1[8 * 64 + t];
        float ls = w2f * W1[9 * 64 + t];
#pragma unroll
        for (int off = 32; off; off >>= 1) {
            lc += __shfl_xor(lc, off);
            ls += __shfl_xor(ls, off);
        }
        if (t == 0) { sLc = 0.5f * lc; sLs = 0.5f * ls; }
    } else if (t < 128) {               // diff weights + W2 (0.25 folded)
        int h = t - 64;
        sWc[h] = (_Float16)W1[8 * 64 + h];
        sWs[h] = (_Float16)W1[9 * 64 + h];
        sW2[h] = (_Float16)(0.25f * W2[h]);
    } else if (t < 256) {               // per-row trig
        int r = t - 128;
        int grow = (r < 64) ? (bi * 64 + r) : (bj * 64 + (r - 64));
        float ang = TWO_PI_F * s[grow];
        float c1 = __cosf(ang);
        float s1 = __sinf(ang);
        strig[0][r] = c1;
        strig[1][r] = s1;
        strig[2][r] = c1 * c1 - s1 * s1;   // exact double-angle k=2
        strig[3][r] = 2.0f * c1 * s1;
    }
    __syncthreads();

    // --- phase 1: generate A/B into LDS + per-row linear scalars P ---
    {
        int h  = t & 63;
        int rg = t >> 6;                 // 8 row-groups x 16 rows; wave == row-group
        float w1v[8];
#pragma unroll
        for (int w = 0; w < 8; ++w) w1v[w] = W1[w * 64 + h];
        float zch = zc[h];
        float w2f = W2[h];
#pragma unroll
        for (int rr = 0; rr < 16; ++rr) {
            int row = rg * 16 + rr;
            float c1 = strig[0][row], s1 = strig[1][row];
            float c2 = strig[2][row], s2 = strig[3][row];
            float A = zch;
            A = fmaf(c1, w1v[0], A);
            A = fmaf(s1, w1v[1], A);
            A = fmaf(c2, w1v[2], A);
            A = fmaf(s2, w1v[3], A);
            float B = c1 * w1v[4];
            B = fmaf(s1, w1v[5], B);
            B = fmaf(c2, w1v[6], B);
            B = fmaf(s2, w1v[7], B);
            int arr = (row >> 6) * 2;    // 0: i-rows, 2: j-rows
            int lr  = row & 63;
            int col = h ^ (((lr >> 2) & 7) << 3);
            sAB[arr + 0][lr][col] = (_Float16)A;
            sAB[arr + 1][lr][col] = (_Float16)B;
            // P[row] = sum_h w2*(A+B): full-wave shuffle reduce (lanes == h)
            float pv = w2f * (A + B);
#pragma unroll
            for (int off = 32; off; off >>= 1) pv += __shfl_xor(pv, off);
            if (h == 0) sPq[row] = 0.25f * pv;
        }
    }
    __syncthreads();

    // --- phase 2: 2x4 patch per thread, forced-packed f16 ---
    int tj4 = t & 15;
    int ti2 = t >> 4;

    float ctf[2][4], stf[2][4];
    h2 ct2[2][4], st2[2][4];
#pragma unroll
    for (int r = 0; r < 2; ++r) {
        int il = ti2 * 2 + r;
        float ci = strig[0][il], si = strig[1][il];
#pragma unroll
        for (int c = 0; c < 4; ++c) {
            int jl = tj4 * 4 + c;
            float cj = strig[0][64 + jl], sj = strig[1][64 + jl];
            float cv = fmaf(ci, cj, si * sj);              // cos(2pi*dist)
            float sv = fabsf(fmaf(si, cj, -(ci * sj)));    // sin(2pi*dist)
            ctf[r][c] = cv; stf[r][c] = sv;
            _Float16 cth = (_Float16)cv;
            _Float16 sth = (_Float16)sv;
            ct2[r][c] = (h2){cth, cth};
            st2[r][c] = (h2){sth, sth};
        }
    }

    h2 T[2][4];
#pragma unroll
    for (int r = 0; r < 2; ++r)
#pragma unroll
        for (int c = 0; c < 4; ++c) T[r][c] = (h2)0;

    int rbase[2], rkey[2], cbase[4], ckey[4];
#pragma unroll
    for (int r = 0; r < 2; ++r) {
        int il = ti2 * 2 + r;
        rbase[r] = il * 64;
        rkey[r]  = ((il >> 2) & 7) << 3;
    }
#pragma unroll
    for (int c = 0; c < 4; ++c) {
        int jl = tj4 * 4 + c;
        cbase[c] = jl * 64;
        ckey[c]  = ((jl >> 2) & 7) << 3;
    }

    const _Float16* pAi = &sAB[0][0][0];
    const _Float16* pBi = &sAB[1][0][0];
    const _Float16* pAj = &sAB[2][0][0];
    const _Float16* pBj = &sAB[3][0][0];

#pragma unroll
    for (int hg = 0; hg < 8; ++hg) {
        const int h0 = hg * 8;
        V8 wc8, ws8, w28;
        wc8.v = *(const u32x4*)&sWc[h0];        // uniform addr -> broadcast
        ws8.v = *(const u32x4*)&sWs[h0];
        w28.v = *(const u32x4*)&sW2[h0];

        V8 ai8[2], bi8[2], aj8[4], bj8[4];
#pragma unroll
        for (int r = 0; r < 2; ++r) {
            ai8[r].v = *(const u32x4*)&pAi[rbase[r] + (h0 ^ rkey[r])];
            bi8[r].v = *(const u32x4*)&pBi[rbase[r] + (h0 ^ rkey[r])];
        }
#pragma unroll
        for (int c = 0; c < 4; ++c) {
            aj8[c].v = *(const u32x4*)&pAj[cbase[c] + (h0 ^ ckey[c])];
            bj8[c].v = *(const u32x4*)&pBj[cbase[c] + (h0 ^ ckey[c])];
        }

#pragma unroll
        for (int r = 0; r < 2; ++r) {
#pragma unroll
            for (int c = 0; c < 4; ++c) {
                h2 ct = ct2[r][c];
                h2 st = st2[r][c];
#pragma unroll
                for (int k = 0; k < 4; ++k) {
                    h2 d2 = pk_fma(st, ws8.h[k], pk_mul(ct, wc8.h[k]));
                    h2 p1 = pk_add(pk_add(ai8[r].h[k], bj8[c].h[k]), d2);
                    h2 p2 = pk_add(pk_add(aj8[c].h[k], bi8[r].h[k]), d2);
                    T[r][c] = pk_fma(pk_add(habs2(p1), habs2(p2)),
                                     w28.h[k], T[r][c]);
                }
            }
        }
    }

    float b2 = b2v[0];
    float vals[2][4];
#pragma unroll
    for (int r = 0; r < 2; ++r) {
        int il = ti2 * 2 + r;
        int gi = bi * 64 + il;
        float pqi = sPq[il];
#pragma unroll
        for (int c = 0; c < 4; ++c) {
            int jl = tj4 * 4 + c;
            int gj = bj * 64 + jl;
            float base = b2 + pqi + sPq[64 + jl] +
                         ctf[r][c] * sLc + stf[r][c] * sLs;
            float v = base + (float)T[r][c][0] + (float)T[r][c][1];
            if (gi == gj) v = -1e9f;
            vals[r][c] = v;
        }
    }

    // direct (upper) tile: one float4 store per row
#pragma unroll
    for (int r = 0; r < 2; ++r) {
        int gi = bi * 64 + ti2 * 2 + r;
        f4 o = {vals[r][0], vals[r][1], vals[r][2], vals[r][3]};
        *(f4*)&out[(size_t)gi * N + bj * 64 + tj4 * 4] = o;
    }

    if (bj > bi) {   // mirrored block via LDS transpose (stride 67)
        __syncthreads();
        float* tile = (float*)&sAB[0][0][0];   // 17.2 KB inside sAB
#pragma unroll
        for (int r = 0; r < 2; ++r)
#pragma unroll
            for (int c = 0; c < 4; ++c)
                tile[(ti2 * 2 + r) * 67 + tj4 * 4 + c] = vals[r][c];
        __syncthreads();
#pragma unroll
        for (int r = 0; r < 2; ++r) {
            int orow = ti2 * 2 + r;            // j-space row
            f4 m;
#pragma unroll
            for (int c = 0; c < 4; ++c)
                m[c] = tile[(tj4 * 4 + c) * 67 + orow];
            *(f4*)&out[(size_t)(bj * 64 + orow) * N + bi * 64 + tj4 * 4] = m;
        }
    }
}

extern "C" void kernel_launch(void* const* d_in, const int* in_sizes, int n_in,
                              void* d_out, int out_size, void* d_ws, size_t ws_size,
                              hipStream_t stream) {
    const float* z  = (const float*)d_in[0];  // [32]
    const float* s  = (const float*)d_in[1];  // [N]
    const float* W1 = (const float*)d_in[2];  // [42,64]
    const float* b1 = (const float*)d_in[3];  // [64]
    const float* W2 = (const float*)d_in[4];  // [64]
    const float* b2 = (const float*)d_in[5];  // [1]
    int N = in_sizes[1];                      // 2048

    float* out = (float*)d_out;
    int NB = N / 64;
    int nblk = NB * (NB + 1) / 2;
    gd_fused<<<nblk, 512, 0, stream>>>(z, s, W1, b1, W2, b2, out, N, NB);
}

// Round 8
// 40.092 us; speedup vs baseline: 1.1971x; 1.1971x over previous
//
#include <hip/hip_runtime.h>
#include <math.h>

#define TWO_PI_F 6.28318530717958647692f

typedef unsigned int u32;
typedef __attribute__((ext_vector_type(4))) u32      u32x4;
typedef __attribute__((ext_vector_type(2))) float    f2;
typedef __attribute__((ext_vector_type(2))) _Float16 h2;

union V8 { u32x4 v; h2 h[4]; };

// ---------------------------------------------------------------------------
// Fused kernel, 32x32 output tile per block, upper-triangular blocks only.
// 2080 blocks of 256 threads (4 waves) -> ~8 blocks/CU, up to 32 waves/CU
// (vs 2 blocks x 8 waves before: occupancy was the binding constraint).
// Each block regenerates its A/B projections in-LDS:
//   A[r,h] = zc[h] + pe(s_r) @ W1[0:4,h]   (zc = b1 + z @ W1[10:42])
//   B[r,h] = pe(s_r) @ W1[4:8,h]
// LDS layout: sAB[arr][row][h ^ (((row>>2)&7)<<3)] -> all hot ds ops <=2-way.
// Each thread owns a 2x2 patch, evaluates BOTH orientations (shared diff
// term) in packed f16 builtins, writes symmetrized tile + mirror via LDS
// transpose.
// ---------------------------------------------------------------------------
__global__ __launch_bounds__(256, 8) void gd_fused(
    const float* __restrict__ z,  const float* __restrict__ s,
    const float* __restrict__ W1, const float* __restrict__ b1,
    const float* __restrict__ W2, const float* __restrict__ b2v,
    float* __restrict__ out, int N, int NB)
{
    __shared__ __attribute__((aligned(16))) _Float16 sAB[4][32][64]; // Ai,Bi,Aj,Bj
    __shared__ __attribute__((aligned(16))) _Float16 sWc[64], sWs[64], sW2[64];
    __shared__ float strig[4][64];    // c1,s1,c2,s2 per local row (0:31=i, 32:63=j)
    __shared__ float zc[64];

    // --- triangular block decode: u -> (bi, bj), bj >= bi ---
    int u = blockIdx.x;
    int M = 2 * NB + 1;
    float disc = (float)(M * M - 8 * u);
    int bi = (int)(((float)M - sqrtf(disc)) * 0.5f);
    if (bi < 0) bi = 0;
    if (bi > NB - 1) bi = NB - 1;
    while (bi > 0 && bi * (M - bi) / 2 > u) --bi;
    while ((bi + 1) * (M - (bi + 1)) / 2 <= u) ++bi;
    int bj = bi + (u - bi * (M - bi) / 2);

    int t = threadIdx.x;

    // --- setup phase: disjoint thread ranges, one barrier ---
    if (t < 64) {                       // zc = b1 + z @ W1[10:42]
        float acc = b1[t];
#pragma unroll
        for (int zz = 0; zz < 32; ++zz)
            acc = fmaf(z[zz], W1[(10 + zz) * 64 + t], acc);
        zc[t] = acc;
    } else if (t < 128) {               // diff weights + W2 (0.5 folded)
        int h = t - 64;
        sWc[h] = (_Float16)W1[8 * 64 + h];
        sWs[h] = (_Float16)W1[9 * 64 + h];
        sW2[h] = (_Float16)(0.5f * W2[h]);
    } else if (t < 192) {               // per-row trig (32 i-rows, 32 j-rows)
        int r = t - 128;
        int grow = (r < 32) ? (bi * 32 + r) : (bj * 32 + (r - 32));
        float ang = TWO_PI_F * s[grow];
        float c1 = __cosf(ang);
        float s1 = __sinf(ang);
        strig[0][r] = c1;
        strig[1][r] = s1;
        strig[2][r] = c1 * c1 - s1 * s1;   // exact double-angle k=2
        strig[3][r] = 2.0f * c1 * s1;
    }
    __syncthreads();

    // --- phase 1: generate A/B projections into LDS ---
    {
        int h  = t & 63;
        int rg = t >> 6;                 // 4 row-groups x 16 rows
        float w1v[8];
#pragma unroll
        for (int w = 0; w < 8; ++w) w1v[w] = W1[w * 64 + h];
        float zch = zc[h];
#pragma unroll
        for (int rr = 0; rr < 16; ++rr) {
            int row = rg * 16 + rr;      // 0..63
            float c1 = strig[0][row], s1 = strig[1][row];
            float c2 = strig[2][row], s2 = strig[3][row];
            float A = zch;
            A = fmaf(c1, w1v[0], A);
            A = fmaf(s1, w1v[1], A);
            A = fmaf(c2, w1v[2], A);
            A = fmaf(s2, w1v[3], A);
            float B = c1 * w1v[4];
            B = fmaf(s1, w1v[5], B);
            B = fmaf(c2, w1v[6], B);
            B = fmaf(s2, w1v[7], B);
            int arr = (row >> 5) * 2;    // 0: i-rows, 2: j-rows
            int lr  = row & 31;
            int col = h ^ (((lr >> 2) & 7) << 3);
            sAB[arr + 0][lr][col] = (_Float16)A;
            sAB[arr + 1][lr][col] = (_Float16)B;
        }
    }
    __syncthreads();

    // --- phase 2: 2x2 patch per thread, packed-f16 builtins ---
    int tj = t & 15;    // col pair: jl = tj*2 + c
    int ti = t >> 4;    // row pair: il = ti*2 + r

    h2 ct2[2][2], st2[2][2];
#pragma unroll
    for (int r = 0; r < 2; ++r) {
        int il = ti * 2 + r;
        float ci = strig[0][il], si = strig[1][il];
#pragma unroll
        for (int c = 0; c < 2; ++c) {
            int jl = tj * 2 + c;
            float cj = strig[0][32 + jl], sj = strig[1][32 + jl];
            float cv = fmaf(ci, cj, si * sj);              // cos(2pi*dist)
            float sv = fabsf(fmaf(si, cj, -(ci * sj)));    // sin(2pi*dist)
            _Float16 cth = (_Float16)cv;
            _Float16 sth = (_Float16)sv;
            ct2[r][c] = (h2){cth, cth};
            st2[r][c] = (h2){sth, sth};
        }
    }

    h2 acc1[2][2], acc2[2][2];
#pragma unroll
    for (int r = 0; r < 2; ++r)
#pragma unroll
        for (int c = 0; c < 2; ++c) { acc1[r][c] = (h2)0; acc2[r][c] = (h2)0; }

    int rbase[2], rkey[2], cbase[2], ckey[2];
#pragma unroll
    for (int r = 0; r < 2; ++r) {
        int il = ti * 2 + r;
        rbase[r] = il * 64;
        rkey[r]  = ((il >> 2) & 7) << 3;
    }
#pragma unroll
    for (int c = 0; c < 2; ++c) {
        int jl = tj * 2 + c;
        cbase[c] = jl * 64;
        ckey[c]  = ((jl >> 2) & 7) << 3;
    }

    const _Float16* pAi = &sAB[0][0][0];
    const _Float16* pBi = &sAB[1][0][0];
    const _Float16* pAj = &sAB[2][0][0];
    const _Float16* pBj = &sAB[3][0][0];

#pragma unroll 2
    for (int hg = 0; hg < 8; ++hg) {
        const int h0 = hg * 8;
        V8 wc8, ws8, w28;
        wc8.v = *(const u32x4*)&sWc[h0];        // uniform addr -> broadcast
        ws8.v = *(const u32x4*)&sWs[h0];
        w28.v = *(const u32x4*)&sW2[h0];

        V8 ai8[2], bi8[2], aj8[2], bj8[2];
#pragma unroll
        for (int r = 0; r < 2; ++r) {
            ai8[r].v = *(const u32x4*)&pAi[rbase[r] + (h0 ^ rkey[r])];
            bi8[r].v = *(const u32x4*)&pBi[rbase[r] + (h0 ^ rkey[r])];
        }
#pragma unroll
        for (int c = 0; c < 2; ++c) {
            aj8[c].v = *(const u32x4*)&pAj[cbase[c] + (h0 ^ ckey[c])];
            bj8[c].v = *(const u32x4*)&pBj[cbase[c] + (h0 ^ ckey[c])];
        }

#pragma unroll
        for (int r = 0; r < 2; ++r) {
#pragma unroll
            for (int c = 0; c < 2; ++c) {
                h2 ct = ct2[r][c];
                h2 st = st2[r][c];
#pragma unroll
                for (int k = 0; k < 4; ++k) {
                    h2 d2 = __builtin_elementwise_fma(ct, wc8.h[k], st * ws8.h[k]);
                    h2 p1 = ai8[r].h[k] + bj8[c].h[k] + d2;   // orientation (i,j)
                    h2 p2 = aj8[c].h[k] + bi8[r].h[k] + d2;   // orientation (j,i)
                    acc1[r][c] = __builtin_elementwise_fma(
                        __builtin_elementwise_max(p1, (h2)0), w28.h[k], acc1[r][c]);
                    acc2[r][c] = __builtin_elementwise_fma(
                        __builtin_elementwise_max(p2, (h2)0), w28.h[k], acc2[r][c]);
                }
            }
        }
    }

    float b2 = b2v[0];
    float vals[2][2];
#pragma unroll
    for (int r = 0; r < 2; ++r) {
        int gi = bi * 32 + ti * 2 + r;
#pragma unroll
        for (int c = 0; c < 2; ++c) {
            int gj = bj * 32 + tj * 2 + c;
            float v = (float)acc1[r][c][0] + (float)acc1[r][c][1] +
                      (float)acc2[r][c][0] + (float)acc2[r][c][1] + b2;
            if (gi == gj) v = -1e9f;
            vals[r][c] = v;
        }
    }

    // direct (upper) tile: one float2 store per row
#pragma unroll
    for (int r = 0; r < 2; ++r) {
        int gi = bi * 32 + ti * 2 + r;
        f2 o = {vals[r][0], vals[r][1]};
        *(f2*)&out[(size_t)gi * N + bj * 32 + tj * 2] = o;
    }

    if (bj > bi) {   // mirrored block via LDS transpose (stride 33)
        __syncthreads();
        float* tile = (float*)&sAB[0][0][0];   // 32*33*4 = 4.2 KB inside sAB
#pragma unroll
        for (int r = 0; r < 2; ++r)
#pragma unroll
            for (int c = 0; c < 2; ++c)
                tile[(ti * 2 + r) * 33 + tj * 2 + c] = vals[r][c];
        __syncthreads();
#pragma unroll
        for (int r = 0; r < 2; ++r) {
            int orow = ti * 2 + r;             // j-space row
            f2 m = {tile[(tj * 2 + 0) * 33 + orow],
                    tile[(tj * 2 + 1) * 33 + orow]};
            *(f2*)&out[(size_t)(bj * 32 + orow) * N + bi * 32 + tj * 2] = m;
        }
    }
}

extern "C" void kernel_launch(void* const* d_in, const int* in_sizes, int n_in,
                              void* d_out, int out_size, void* d_ws, size_t ws_size,
                              hipStream_t stream) {
    const float* z  = (const float*)d_in[0];  // [32]
    const float* s  = (const float*)d_in[1];  // [N]
    const float* W1 = (const float*)d_in[2];  // [42,64]
    const float* b1 = (const float*)d_in[3];  // [64]
    const float* W2 = (const float*)d_in[4];  // [64]
    const float* b2 = (const float*)d_in[5];  // [1]
    int N = in_sizes[1];                      // 2048

    float* out = (float*)d_out;
    int NB = N / 32;
    int nblk = NB * (NB + 1) / 2;             // 2080 for N=2048
    gd_fused<<<nblk, 256, 0, stream>>>(z, s, W1, b1, W2, b2, out, N, NB);
}

// Round 9
// 35.885 us; speedup vs baseline: 1.3375x; 1.1173x over previous
//
#include <hip/hip_runtime.h>
#include <math.h>

#define TWO_PI_F 6.28318530717958647692f

typedef unsigned int u32;
typedef __attribute__((ext_vector_type(4))) u32      u32x4;
typedef __attribute__((ext_vector_type(4))) float    f4;
typedef __attribute__((ext_vector_type(2))) _Float16 h2;

union V8 { u32x4 v; h2 h[4]; };

#if __has_builtin(__builtin_amdgcn_fdot2)
#define FDOT2(a, b, c) __builtin_amdgcn_fdot2((a), (b), (c), false)
#else
__device__ __forceinline__ float FDOT2(h2 a, h2 b, float c) {
    return c + (float)a[0] * (float)b[0] + (float)a[1] * (float)b[1];
}
#endif

// ---------------------------------------------------------------------------
// Fused kernel: 32x32 output tile per block, upper-triangular blocks only
// (2080 blocks). 128 threads (2 waves), each thread owns a 2x4 patch ->
// 15 ds_read_b128 per 8 cells per h-group (vs 11 per 4 before). Accumulation
// via v_dot2_f32_f16 into f32 scalars (guaranteed packed multiply-accum).
// A/B projections regenerated in-LDS; XOR-swizzled layout keeps all hot LDS
// ops <=2-way.
// ---------------------------------------------------------------------------
__global__ __launch_bounds__(128) void gd_fused(
    const float* __restrict__ z,  const float* __restrict__ s,
    const float* __restrict__ W1, const float* __restrict__ b1,
    const float* __restrict__ W2, const float* __restrict__ b2v,
    float* __restrict__ out, int N, int NB)
{
    __shared__ __attribute__((aligned(16))) _Float16 sAB[4][32][64]; // Ai,Bi,Aj,Bj
    __shared__ __attribute__((aligned(16))) _Float16 sWc[64], sWs[64], sW2[64];
    __shared__ __attribute__((aligned(16))) f4 strig2[64]; // {c1,s1,c2,s2}; 0:31=i rows, 32:63=j rows
    __shared__ float zc[64];

    // --- triangular block decode: u -> (bi, bj), bj >= bi ---
    int u = blockIdx.x;
    int M = 2 * NB + 1;
    float disc = (float)(M * M - 8 * u);
    int bi = (int)(((float)M - sqrtf(disc)) * 0.5f);
    if (bi < 0) bi = 0;
    if (bi > NB - 1) bi = NB - 1;
    while (bi > 0 && bi * (M - bi) / 2 > u) --bi;
    while ((bi + 1) * (M - (bi + 1)) / 2 <= u) ++bi;
    int bj = bi + (u - bi * (M - bi) / 2);

    int t = threadIdx.x;

    // --- setup: t<64 does trig(row t) + zc[t]; t>=64 stages weights ---
    if (t < 64) {
        int grow = (t < 32) ? (bi * 32 + t) : (bj * 32 + (t - 32));
        float ang = TWO_PI_F * s[grow];
        float c1 = __cosf(ang);
        float s1 = __sinf(ang);
        strig2[t] = (f4){c1, s1, c1 * c1 - s1 * s1, 2.0f * c1 * s1};
        float acc = b1[t];
#pragma unroll
        for (int zz = 0; zz < 32; ++zz)
            acc = fmaf(z[zz], W1[(10 + zz) * 64 + t], acc);
        zc[t] = acc;
    } else {
        int h = t - 64;
        sWc[h] = (_Float16)W1[8 * 64 + h];
        sWs[h] = (_Float16)W1[9 * 64 + h];
        sW2[h] = (_Float16)(0.5f * W2[h]);   // fold 0.5 symmetrization
    }
    __syncthreads();

    // --- phase 1: generate A/B pairs (2 h per thread) into swizzled LDS ---
    {
        int q  = t & 31;          // h-pair index: h = 2q, 2q+1
        int rg = t >> 5;          // 4 row-groups x 16 rows
        float w1a[8], w1b[8];
#pragma unroll
        for (int w = 0; w < 8; ++w) {
            w1a[w] = W1[w * 64 + 2 * q];
            w1b[w] = W1[w * 64 + 2 * q + 1];
        }
        float z0 = zc[2 * q], z1 = zc[2 * q + 1];
#pragma unroll
        for (int rr = 0; rr < 16; ++rr) {
            int row = rg * 16 + rr;           // 0..63
            f4 tg = strig2[row];
            float A0 = z0, A1 = z1;
            A0 = fmaf(tg.x, w1a[0], A0); A1 = fmaf(tg.x, w1b[0], A1);
            A0 = fmaf(tg.y, w1a[1], A0); A1 = fmaf(tg.y, w1b[1], A1);
            A0 = fmaf(tg.z, w1a[2], A0); A1 = fmaf(tg.z, w1b[2], A1);
            A0 = fmaf(tg.w, w1a[3], A0); A1 = fmaf(tg.w, w1b[3], A1);
            float B0 = tg.x * w1a[4], B1 = tg.x * w1b[4];
            B0 = fmaf(tg.y, w1a[5], B0); B1 = fmaf(tg.y, w1b[5], B1);
            B0 = fmaf(tg.z, w1a[6], B0); B1 = fmaf(tg.z, w1b[6], B1);
            B0 = fmaf(tg.w, w1a[7], B0); B1 = fmaf(tg.w, w1b[7], B1);
            int arr = (row >> 5) * 2;         // 0: i-rows, 2: j-rows
            int lr  = row & 31;
            int colq = q ^ (((lr >> 2) & 7) << 2);   // pair-unit swizzle
            h2 Aw = {(_Float16)A0, (_Float16)A1};
            h2 Bw = {(_Float16)B0, (_Float16)B1};
            *(h2*)&sAB[arr + 0][lr][2 * colq] = Aw;
            *(h2*)&sAB[arr + 1][lr][2 * colq] = Bw;
        }
    }
    __syncthreads();

    // --- phase 2: 2x4 patch per thread ---
    int tj = t & 7;     // col quad: jl = tj*4 + c
    int ti = t >> 3;    // row pair: il = ti*2 + r

    int RK = ((ti >> 1) & 7) << 3;   // row swizzle key (same for both rows)
    int CK = (tj & 7) << 3;          // col swizzle key (same for all 4 cols)

    h2 ct2[2][4], st2[2][4];
#pragma unroll
    for (int r = 0; r < 2; ++r) {
        int il = ti * 2 + r;
        f4 tgi = strig2[il];
#pragma unroll
        for (int c = 0; c < 4; ++c) {
            int jl = tj * 4 + c;
            f4 tgj = strig2[32 + jl];
            float cv = fmaf(tgi.x, tgj.x, tgi.y * tgj.y);            // cos(2pi*dist)
            float sv = fabsf(fmaf(tgi.y, tgj.x, -(tgi.x * tgj.y)));  // sin(2pi*dist)
            _Float16 cth = (_Float16)cv;
            _Float16 sth = (_Float16)sv;
            ct2[r][c] = (h2){cth, cth};
            st2[r][c] = (h2){sth, sth};
        }
    }

    float acc[2][4];
#pragma unroll
    for (int r = 0; r < 2; ++r)
#pragma unroll
        for (int c = 0; c < 4; ++c) acc[r][c] = 0.0f;

    int rbase[2], cbase[4];
#pragma unroll
    for (int r = 0; r < 2; ++r) rbase[r] = (ti * 2 + r) * 64;
#pragma unroll
    for (int c = 0; c < 4; ++c) cbase[c] = (tj * 4 + c) * 64;

    const _Float16* pAi = &sAB[0][0][0];
    const _Float16* pBi = &sAB[1][0][0];
    const _Float16* pAj = &sAB[2][0][0];
    const _Float16* pBj = &sAB[3][0][0];

#pragma unroll
    for (int hg = 0; hg < 8; ++hg) {
        const int h0 = hg * 8;
        V8 wc8, ws8, w28;
        wc8.v = *(const u32x4*)&sWc[h0];        // uniform addr -> broadcast
        ws8.v = *(const u32x4*)&sWs[h0];
        w28.v = *(const u32x4*)&sW2[h0];

        const int oR = h0 ^ RK;
        const int oC = h0 ^ CK;

        V8 ai8[2], bi8[2], aj8[4], bj8[4];
#pragma unroll
        for (int r = 0; r < 2; ++r) {
            ai8[r].v = *(const u32x4*)&pAi[rbase[r] + oR];
            bi8[r].v = *(const u32x4*)&pBi[rbase[r] + oR];
        }
#pragma unroll
        for (int c = 0; c < 4; ++c) {
            aj8[c].v = *(const u32x4*)&pAj[cbase[c] + oC];
            bj8[c].v = *(const u32x4*)&pBj[cbase[c] + oC];
        }

#pragma unroll
        for (int r = 0; r < 2; ++r) {
#pragma unroll
            for (int c = 0; c < 4; ++c) {
                h2 ct = ct2[r][c];
                h2 st = st2[r][c];
#pragma unroll
                for (int k = 0; k < 4; ++k) {
                    h2 d2 = __builtin_elementwise_fma(ct, wc8.h[k], st * ws8.h[k]);
                    h2 p1 = ai8[r].h[k] + bj8[c].h[k] + d2;   // (i,j)
                    h2 p2 = aj8[c].h[k] + bi8[r].h[k] + d2;   // (j,i)
                    h2 m  = __builtin_elementwise_max(p1, (h2)0) +
                            __builtin_elementwise_max(p2, (h2)0);
                    acc[r][c] = FDOT2(m, w28.h[k], acc[r][c]);
                }
            }
        }
    }

    float b2 = b2v[0];
    float vals[2][4];
#pragma unroll
    for (int r = 0; r < 2; ++r) {
        int gi = bi * 32 + ti * 2 + r;
#pragma unroll
        for (int c = 0; c < 4; ++c) {
            int gj = bj * 32 + tj * 4 + c;
            float v = acc[r][c] + b2;
            if (gi == gj) v = -1e9f;
            vals[r][c] = v;
        }
    }

    // direct (upper) tile: one float4 store per row
#pragma unroll
    for (int r = 0; r < 2; ++r) {
        int gi = bi * 32 + ti * 2 + r;
        f4 o = {vals[r][0], vals[r][1], vals[r][2], vals[r][3]};
        *(f4*)&out[(size_t)gi * N + bj * 32 + tj * 4] = o;
    }

    if (bj > bi) {   // mirrored block via LDS transpose (stride 33)
        __syncthreads();
        float* tile = (float*)&sAB[0][0][0];   // 32*33*4 = 4.2 KB inside sAB
#pragma unroll
        for (int r = 0; r < 2; ++r)
#pragma unroll
            for (int c = 0; c < 4; ++c)
                tile[(ti * 2 + r) * 33 + tj * 4 + c] = vals[r][c];
        __syncthreads();
#pragma unroll
        for (int r = 0; r < 2; ++r) {
            int orow = ti * 2 + r;             // j-space row
            f4 m;
#pragma unroll
            for (int c = 0; c < 4; ++c)
                m[c] = tile[(tj * 4 + c) * 33 + orow];
            *(f4*)&out[(size_t)(bj * 32 + orow) * N + bi * 32 + tj * 4] = m;
        }
    }
}

extern "C" void kernel_launch(void* const* d_in, const int* in_sizes, int n_in,
                              void* d_out, int out_size, void* d_ws, size_t ws_size,
                              hipStream_t stream) {
    const float* z  = (const float*)d_in[0];  // [32]
    const float* s  = (const float*)d_in[1];  // [N]
    const float* W1 = (const float*)d_in[2];  // [42,64]
    const float* b1 = (const float*)d_in[3];  // [64]
    const float* W2 = (const float*)d_in[4];  // [64]
    const float* b2 = (const float*)d_in[5];  // [1]
    int N = in_sizes[1];                      // 2048

    float* out = (float*)d_out;
    int NB = N / 32;
    int nblk = NB * (NB + 1) / 2;             // 2080 for N=2048
    gd_fused<<<nblk, 128, 0, stream>>>(z, s, W1, b1, W2, b2, out, N, NB);
}